// Round 1
// baseline (227.295 us; speedup 1.0000x reference)
//
#include <hip/hip_runtime.h>
#include <stdint.h>

typedef unsigned int u32;
typedef unsigned short u16;

#define N_  1024
#define F_  512
#define ALPHA 0.2f
#define TSTR 68   // k_prep LDS tile stride (u16): 136 B rows -> uint2-aligned reads, ~4-way write conflicts

typedef __attribute__((ext_vector_type(8))) short short8;
typedef __attribute__((ext_vector_type(4))) float float4v;

union Frag { short8 s; u32 u[4]; };

static __device__ __forceinline__ float bits2f(u32 b){ union{u32 u; float f;} c; c.u=b; return c.f; }
static __device__ __forceinline__ u32   f2bits(float f){ union{float f_; u32 u;} c; c.f_=f; return c.u; }
static __device__ __forceinline__ float bflo(u32 p){ return bits2f(p<<16); }
static __device__ __forceinline__ float bfhi(u32 p){ return bits2f(p & 0xffff0000u); }
static __device__ __forceinline__ u32   f2bf(float f){ u32 u=f2bits(f); return (u + 0x7fffu + ((u>>16)&1u))>>16; }

// async global->LDS, 16 B per lane; LDS dest = wave-uniform base + lane*16
static __device__ __forceinline__ void gload_lds16(const void* g, void* l){
    __builtin_amdgcn_global_load_lds((const __attribute__((address_space(1))) u32*)g,
                                     (__attribute__((address_space(3))) u32*)l, 16, 0, 0);
}

// ---- kernel 1: w1 = W^T a1, w2 = W^T a2 (atomic partial sums into ws[0..1024)) ----
__global__ void k_w12(const float* __restrict__ W, const float* __restrict__ a1,
                      const float* __restrict__ a2, float* __restrict__ ws){
    int t = threadIdx.x;          // 256 threads: f = t and t+256
    int bo = blockIdx.x;          // 64 blocks: o-chunk of 8
    float s1a=0.f,s2a=0.f,s1b=0.f,s2b=0.f;
    #pragma unroll
    for(int i=0;i<8;i++){
        int o = bo*8+i;
        float av1 = a1[o], av2 = a2[o];
        float wa = W[o*F_ + t], wb = W[o*F_ + t + 256];
        s1a += wa*av1; s2a += wa*av2; s1b += wb*av1; s2b += wb*av2;
    }
    atomicAdd(&ws[t],       s1a); atomicAdd(&ws[512+t],     s2a);
    atomicAdd(&ws[t+256],   s1b); atomicAdd(&ws[512+t+256], s2b);
}

// ---- kernel 2: fused transpose + dot accumulation ----
// X fp32 [b][m][f] -> XT bf16 [b][f][m]; also d1acc[r] += X[r,:].w1, d2acc += X[r,:].w2 (fp32 atomics)
__global__ __launch_bounds__(256)
void k_prep(const float* __restrict__ X, const float* __restrict__ ws,
            u16* __restrict__ XT, float* __restrict__ d1acc, float* __restrict__ d2acc){
    __shared__ u16 tile[64*TSTR];
    const int t  = threadIdx.x;
    const int m0 = blockIdx.x*64, f0 = blockIdx.y*64, b = blockIdx.z;
    const int ml = t>>4, fl4 = (t&15)*4;
    float4 w1q = *(const float4*)(ws + f0 + fl4);
    float4 w2q = *(const float4*)(ws + 512 + f0 + fl4);
    float d1p[4], d2p[4];
    #pragma unroll
    for(int rr=0;rr<4;rr++){
        int m = ml + rr*16;
        float4 v = *(const float4*)(X + ((size_t)(b*N_ + m0 + m))*F_ + f0 + fl4);
        tile[(fl4+0)*TSTR + m] = (u16)f2bf(v.x);
        tile[(fl4+1)*TSTR + m] = (u16)f2bf(v.y);
        tile[(fl4+2)*TSTR + m] = (u16)f2bf(v.z);
        tile[(fl4+3)*TSTR + m] = (u16)f2bf(v.w);
        d1p[rr] = v.x*w1q.x + v.y*w1q.y + v.z*w1q.z + v.w*w1q.w;
        d2p[rr] = v.x*w2q.x + v.y*w2q.y + v.z*w2q.z + v.w*w2q.w;
    }
    #pragma unroll
    for(int s=1;s<16;s<<=1){
        #pragma unroll
        for(int rr=0;rr<4;rr++){ d1p[rr] += __shfl_xor(d1p[rr],s,64); d2p[rr] += __shfl_xor(d2p[rr],s,64); }
    }
    if((t&15)==0){
        #pragma unroll
        for(int rr=0;rr<4;rr++){
            atomicAdd(&d1acc[b*N_ + m0 + ml + rr*16], d1p[rr]);
            atomicAdd(&d2acc[b*N_ + m0 + ml + rr*16], d2p[rr]);
        }
    }
    __syncthreads();
    const int fl = t>>4, ml4 = (t&15)*4;
    #pragma unroll
    for(int rr=0;rr<4;rr++){
        int f = fl + rr*16;
        uint2 val = *(const uint2*)(&tile[f*TSTR + ml4]);
        *(uint2*)(XT + ((size_t)(b*F_ + f0 + f))*N_ + m0 + ml4) = val;
    }
}

// ---- kernel 3: fused scores+softmax+PV+ELU ----
// grid (32 n-blocks, 16 b) = 512 blocks -> 2 blocks/CU (LDS 68KB x2 <= 160KB).
// block 512 = 8 waves: (nsub 0..1) x (fh 0..3). wave: 16 n-rows x 128 f.
// m-chunks of 32, double-buffered async LDS staging of XT (layout unchanged).
// e1/e2 exp tables computed in-kernel (k_exp folded in).
__global__ __launch_bounds__(512, 4)
void k_main(const u16* __restrict__ XT, const int* __restrict__ adj,
            const float* __restrict__ d1acc, const float* __restrict__ d2acc,
            float* __restrict__ out){
    __shared__ u16 xbuf[2][2][8192];   // [dbuf][fhalf][16 ct * 512 u16], 64 KB
    __shared__ u32 lds_e2[N_];         // 4 KB

    const int t    = threadIdx.x;
    const int lane = t & 63;
    const int wv   = t >> 6;           // 0..7
    const int nsub = wv & 1;           // 2 row-groups of 16
    const int fh   = wv >> 1;          // 0..3: f-quarter of 128
    const int b    = blockIdx.y;
    const int n0   = blockIdx.x * 32;
    const int r16  = lane & 15;
    const int quad = lane >> 4;
    const int nrow = n0 + nsub*16 + r16;

    // build exp(f2)/exp(.2*f2) bf16-pair table in LDS (was k_exp); 2 entries/thread
    {
        float2 dv = *(const float2*)(d2acc + (size_t)b*N_ + t*2);
        u32 w0 = f2bf(__expf(dv.x)) | (f2bf(__expf(ALPHA*dv.x))<<16);
        u32 w1 = f2bf(__expf(dv.y)) | (f2bf(__expf(ALPHA*dv.y))<<16);
        lds_e2[t*2]   = w0;
        lds_e2[t*2+1] = w1;
    }
    const float d1v  = d1acc[b*N_ + nrow];
    const float e1pR = __expf(d1v);
    const float e1nR = __expf(ALPHA*d1v);
    const int* adjRow = adj + ((size_t)(b*N_ + nrow))*N_ + quad*8;
    const u16* XTb = XT + (size_t)b*F_*N_;

    // stage chunk 0 -> buf 0 (32 calls split over 8 waves; lane l covers f=c*16+(l&15), m=(l>>4)*8)
    #pragma unroll
    for(int k=0;k<4;k++){
        int idx = wv*4 + k, fhh = idx>>4, c = idx&15;
        const u16* g = XTb + (size_t)(fhh*256 + c*16 + r16)*N_ + quad*8;
        gload_lds16(g, &xbuf[0][fhh][c*512]);
    }

    float4v acc[8];
    #pragma unroll
    for(int i=0;i<8;i++) acc[i] = (float4v){0.f,0.f,0.f,0.f};
    float dsum = 0.f;

    int adA[8], adB[8];
    *(int4*)(adA)   = *(const int4*)(adjRow);
    *(int4*)(adA+4) = *(const int4*)(adjRow + 4);
    *(int4*)(adB)   = *(const int4*)(adjRow + 32);
    *(int4*)(adB+4) = *(const int4*)(adjRow + 36);

    int db = 0;
    for(int i=0;i<32;i++){
        const int m0 = i*32;
        __syncthreads();               // staging for xbuf[db] complete (vmcnt drain at barrier)
        if(i < 31){
            const int ms = m0 + 32;
            #pragma unroll
            for(int k=0;k<4;k++){
                int idx = wv*4 + k, fhh = idx>>4, c = idx&15;
                const u16* g = XTb + (size_t)(fhh*256 + c*16 + r16)*N_ + ms + quad*8;
                gload_lds16(g, &xbuf[db^1][fhh][c*512]);
            }
        }
        int pf = (i < 30) ? (m0 + 64) : 0;      // dummy wrap on tail (unused)
        int adC[8];
        *(int4*)(adC)   = *(const int4*)(adjRow + pf);
        *(int4*)(adC+4) = *(const int4*)(adjRow + pf + 4);

        u32 ev[8];
        *(uint4*)(ev)   = *(const uint4*)(&lds_e2[m0 + quad*8]);
        *(uint4*)(ev+4) = *(const uint4*)(&lds_e2[m0 + quad*8 + 4]);

        u32 pb[8];
        #pragma unroll
        for(int j=0;j<8;j++){
            float pp = e1pR * bflo(ev[j]);   // exp(f1)*exp(f2)     = exp(s)
            float pn = e1nR * bfhi(ev[j]);   // exp(.2f1)*exp(.2f2) = exp(.2s)
            float p  = (pp > 1.0f) ? pp : pn;          // lrelu: s>0 <=> exp(s)>1
            p = (adA[j] != 0) ? p : 0.0f;
            dsum += p;
            pb[j] = f2bf(p);
        }
        Frag af;
        af.u[0] = pb[0] | (pb[1]<<16);
        af.u[1] = pb[2] | (pb[3]<<16);
        af.u[2] = pb[4] | (pb[5]<<16);
        af.u[3] = pb[6] | (pb[7]<<16);

        // f-quarter fh: global f = fh*128 + ct*16 + r16 -> fhalf = fh>>1, chunk c = (fh&1)*8 + ct
        const u16* bb = &xbuf[db][fh>>1][((fh&1)*8)*512 + lane*8];   // lane-linear: conflict-free ds_read_b128
        #pragma unroll
        for(int ct=0; ct<8; ct++){
            uint4 bw = *(const uint4*)(bb + ct*512);
            Frag bf_;
            bf_.u[0]=bw.x; bf_.u[1]=bw.y; bf_.u[2]=bw.z; bf_.u[3]=bw.w;
            acc[ct] = __builtin_amdgcn_mfma_f32_16x16x32_bf16(af.s, bf_.s, acc[ct], 0, 0, 0);
        }
        #pragma unroll
        for(int j=0;j<8;j++){ adA[j] = adB[j]; adB[j] = adC[j]; }
        db ^= 1;
    }

    // ---- softmax denominator: in-wave reduce over quads, broadcast to C-layout rows ----
    dsum += __shfl_xor(dsum, 16, 64);
    dsum += __shfl_xor(dsum, 32, 64);
    float invr[4];
    #pragma unroll
    for(int r=0;r<4;r++){
        float dr = __shfl(dsum, quad*4 + r, 64);
        invr[r] = 1.0f / fmaxf(dr, 1e-30f);
    }
    // ---- epilogue: scale, ELU, fp32 store ----
    #pragma unroll
    for(int ct=0; ct<8; ct++){
        #pragma unroll
        for(int r=0;r<4;r++){
            float v = acc[ct][r] * invr[r];
            v = (v > 0.f) ? v : (__expf(v) - 1.f);
            int n_out = n0 + nsub*16 + quad*4 + r;
            out[((size_t)(b*N_ + n_out))*F_ + fh*128 + ct*16 + r16] = v;
        }
    }
}

extern "C" void kernel_launch(void* const* d_in, const int* in_sizes, int n_in,
                              void* d_out, int out_size, void* d_ws, size_t ws_size,
                              hipStream_t stream) {
    const float* X  = (const float*)d_in[0];   // [16,1024,512] fp32
    const int* adj  = (const int*)d_in[1];     // [16,1024,1024] int32
    const float* W  = (const float*)d_in[2];   // [512,512] fp32
    const float* a1 = (const float*)d_in[3];   // [512]
    const float* a2 = (const float*)d_in[4];   // [512]
    float* out = (float*)d_out;                // [16,1024,512] fp32

    float* ws    = (float*)d_ws;
    float* d1acc = ws + 1024;                  // raw sums; exp'd inside k_main now
    float* d2acc = ws + 1024 + 16384;
    u16*  XT     = (u16*)(ws + 50176);         // 16.78 MB bf16 [b][f][m]

    hipMemsetAsync(ws, 0, 33792*sizeof(float), stream);   // zero w1/w2 + d1acc + d2acc
    k_w12<<<64, 256, 0, stream>>>(W, a1, a2, ws);
    k_prep<<<dim3(16, 8, 16), 256, 0, stream>>>(X, ws, XT, d1acc, d2acc);
    k_main<<<dim3(32, 16), 512, 0, stream>>>(XT, adj, d1acc, d2acc, out);
}

// Round 3
// 197.228 us; speedup vs baseline: 1.1524x; 1.1524x over previous
//
#include <hip/hip_runtime.h>
#include <stdint.h>

typedef unsigned int u32;
typedef unsigned short u16;

#define N_  1024
#define F_  512
#define ALPHA 0.2f
#define TSTR 68   // k_prep LDS tile stride (u16): 136 B rows -> uint2-aligned reads, ~4-way write conflicts

typedef __attribute__((ext_vector_type(8))) short short8;
typedef __attribute__((ext_vector_type(4))) float float4v;

union Frag { short8 s; u32 u[4]; };

static __device__ __forceinline__ float bits2f(u32 b){ union{u32 u; float f;} c; c.u=b; return c.f; }
static __device__ __forceinline__ u32   f2bits(float f){ union{float f_; u32 u;} c; c.f_=f; return c.u; }
static __device__ __forceinline__ float bflo(u32 p){ return bits2f(p<<16); }
static __device__ __forceinline__ float bfhi(u32 p){ return bits2f(p & 0xffff0000u); }
static __device__ __forceinline__ u32   f2bf(float f){ u32 u=f2bits(f); return (u + 0x7fffu + ((u>>16)&1u))>>16; }

// async global->LDS, 16 B per lane; LDS dest = wave-uniform base + lane*16
static __device__ __forceinline__ void gload_lds16(const void* g, void* l){
    __builtin_amdgcn_global_load_lds((const __attribute__((address_space(1))) u32*)g,
                                     (__attribute__((address_space(3))) u32*)l, 16, 0, 0);
}

// ---- kernel 1: w1 = W^T a1, w2 = W^T a2 (atomic partial sums into ws[0..1024)) ----
__global__ void k_w12(const float* __restrict__ W, const float* __restrict__ a1,
                      const float* __restrict__ a2, float* __restrict__ ws){
    int t = threadIdx.x;          // 256 threads: f = t and t+256
    int bo = blockIdx.x;          // 64 blocks: o-chunk of 8
    float s1a=0.f,s2a=0.f,s1b=0.f,s2b=0.f;
    #pragma unroll
    for(int i=0;i<8;i++){
        int o = bo*8+i;
        float av1 = a1[o], av2 = a2[o];
        float wa = W[o*F_ + t], wb = W[o*F_ + t + 256];
        s1a += wa*av1; s2a += wa*av2; s1b += wb*av1; s2b += wb*av2;
    }
    atomicAdd(&ws[t],       s1a); atomicAdd(&ws[512+t],     s2a);
    atomicAdd(&ws[t+256],   s1b); atomicAdd(&ws[512+t+256], s2b);
}

// ---- kernel 2: fused transpose + dot accumulation ----
// X fp32 [b][m][f] -> XT bf16 [b][f][m]; also d1acc[r] += X[r,:].w1, d2acc += X[r,:].w2 (fp32 atomics)
__global__ __launch_bounds__(256)
void k_prep(const float* __restrict__ X, const float* __restrict__ ws,
            u16* __restrict__ XT, float* __restrict__ d1acc, float* __restrict__ d2acc){
    __shared__ u16 tile[64*TSTR];
    const int t  = threadIdx.x;
    const int m0 = blockIdx.x*64, f0 = blockIdx.y*64, b = blockIdx.z;
    const int ml = t>>4, fl4 = (t&15)*4;
    float4 w1q = *(const float4*)(ws + f0 + fl4);
    float4 w2q = *(const float4*)(ws + 512 + f0 + fl4);
    float d1p[4], d2p[4];
    #pragma unroll
    for(int rr=0;rr<4;rr++){
        int m = ml + rr*16;
        float4 v = *(const float4*)(X + ((size_t)(b*N_ + m0 + m))*F_ + f0 + fl4);
        tile[(fl4+0)*TSTR + m] = (u16)f2bf(v.x);
        tile[(fl4+1)*TSTR + m] = (u16)f2bf(v.y);
        tile[(fl4+2)*TSTR + m] = (u16)f2bf(v.z);
        tile[(fl4+3)*TSTR + m] = (u16)f2bf(v.w);
        d1p[rr] = v.x*w1q.x + v.y*w1q.y + v.z*w1q.z + v.w*w1q.w;
        d2p[rr] = v.x*w2q.x + v.y*w2q.y + v.z*w2q.z + v.w*w2q.w;
    }
    #pragma unroll
    for(int s=1;s<16;s<<=1){
        #pragma unroll
        for(int rr=0;rr<4;rr++){ d1p[rr] += __shfl_xor(d1p[rr],s,64); d2p[rr] += __shfl_xor(d2p[rr],s,64); }
    }
    if((t&15)==0){
        #pragma unroll
        for(int rr=0;rr<4;rr++){
            atomicAdd(&d1acc[b*N_ + m0 + ml + rr*16], d1p[rr]);
            atomicAdd(&d2acc[b*N_ + m0 + ml + rr*16], d2p[rr]);
        }
    }
    __syncthreads();
    const int fl = t>>4, ml4 = (t&15)*4;
    #pragma unroll
    for(int rr=0;rr<4;rr++){
        int f = fl + rr*16;
        uint2 val = *(const uint2*)(&tile[f*TSTR + ml4]);
        *(uint2*)(XT + ((size_t)(b*F_ + f0 + f))*N_ + m0 + ml4) = val;
    }
}

// ---- kernel 3: fused scores+softmax+PV+ELU ----
// grid (16,16) = 256 blocks = 1 block/CU. block 512 = 8 waves: (nsub 0..3) x (fh 0/1).
// wave: 16 n-rows x 256 f, acc[16]. m-chunks of 32.
// Pipeline: 3 LDS buffers, staging issued 2 bodies ahead, counted s_waitcnt vmcnt(6)
// + raw s_barrier (NOT __syncthreads -> no vmcnt(0) drain). Each body issues exactly
// 6 VMEM ops (4 global_load_lds + 2 adj dwordx4), so vmcnt(6) == "all but newest body".
// XCD-affinity remap: id%8 selects XCD (HW round-robin); all 16 n-blocks of a batch b
// land on XCD b>>1 -> XT[b] chunk read once from L3, 15 L2 hits.
__global__ __launch_bounds__(512, 2)
void k_main(const u16* __restrict__ XT, const int* __restrict__ adj,
            const float* __restrict__ d1acc, const float* __restrict__ d2acc,
            float* __restrict__ out){
    __shared__ u16 xbuf[3][2][8192];   // [buf][fhalf][16 ct * 512 u16], 96 KB triple-buffer
    __shared__ u32 lds_e2[N_];         // 4 KB

    const int t    = threadIdx.x;
    const int lane = t & 63;
    const int wv   = t >> 6;           // 0..7
    const int nsub = wv & 3;
    const int fh   = wv >> 2;
    const int id   = blockIdx.x + (blockIdx.y << 4);   // 0..255
    const int xcd  = id & 7, slot = id >> 3;           // XCD-affinity decode
    const int b    = (xcd << 1) | (slot >> 4);         // 2 batches per XCD
    const int n0   = (slot & 15) << 6;                 // 16 n-blocks of b on same XCD
    const int r16  = lane & 15;
    const int quad = lane >> 4;
    const int nrow = n0 + nsub*16 + r16;

    // build exp(f2)/exp(.2*f2) bf16-pair table in LDS; 2 entries/thread
    {
        float2 dv = *(const float2*)(d2acc + (size_t)b*N_ + t*2);
        lds_e2[t*2]   = f2bf(__expf(dv.x)) | (f2bf(__expf(ALPHA*dv.x))<<16);
        lds_e2[t*2+1] = f2bf(__expf(dv.y)) | (f2bf(__expf(ALPHA*dv.y))<<16);
    }
    const float d1v  = d1acc[b*N_ + nrow];
    const float e1pR = __expf(d1v);
    const float e1nR = __expf(ALPHA*d1v);
    const int* adjRow = adj + ((size_t)(b*N_ + nrow))*N_ + quad*8;
    const u16* XTb = XT + (size_t)b*F_*N_;

    // prologue: stage chunk 0 -> buf0, chunk 1 -> buf1 (32 calls split over 8 waves)
    #pragma unroll
    for(int k=0;k<4;k++){
        int idx = wv*4 + k, fhh = idx>>4, c = idx&15;
        const u16* g = XTb + (size_t)(fhh*256 + c*16 + r16)*N_ + quad*8;
        gload_lds16(g, &xbuf[0][fhh][c*512]);
    }
    #pragma unroll
    for(int k=0;k<4;k++){
        int idx = wv*4 + k, fhh = idx>>4, c = idx&15;
        const u16* g = XTb + (size_t)(fhh*256 + c*16 + r16)*N_ + 32 + quad*8;
        gload_lds16(g, &xbuf[1][fhh][c*512]);
    }

    float4v acc[16];
    #pragma unroll
    for(int i=0;i<16;i++) acc[i] = (float4v){0.f,0.f,0.f,0.f};
    float dsum = 0.f;

    int adA[8], adB[8];
    *(int4*)(adA)   = *(const int4*)(adjRow);
    *(int4*)(adA+4) = *(const int4*)(adjRow + 4);
    *(int4*)(adB)   = *(const int4*)(adjRow + 32);
    *(int4*)(adB+4) = *(const int4*)(adjRow + 36);

    __syncthreads();   // one-time full drain: e2 table + chunks 0,1 resident

    int db = 0;
    for(int i=0;i<32;i++){
        const int m0 = i*32;
        if(i > 0){
            // chunk i staged 2 bodies ago; leave newest body's 6 VMEM ops in flight
            if(i < 31) asm volatile("s_waitcnt vmcnt(6)\n\ts_barrier" ::: "memory");
            else       asm volatile("s_waitcnt vmcnt(0)\n\ts_barrier" ::: "memory");
        }
        if(i < 30){
            const int ms = m0 + 64;            // chunk i+2
            int dbw = db + 2; if(dbw >= 3) dbw -= 3;
            #pragma unroll
            for(int k=0;k<4;k++){
                int idx = wv*4 + k, fhh = idx>>4, c = idx&15;
                const u16* g = XTb + (size_t)(fhh*256 + c*16 + r16)*N_ + ms + quad*8;
                gload_lds16(g, &xbuf[dbw][fhh][c*512]);
            }
        }
        int pf = (i < 30) ? (m0 + 64) : 0;      // dummy wrap on tail (keeps VMEM count uniform)
        int adC[8];
        *(int4*)(adC)   = *(const int4*)(adjRow + pf);
        *(int4*)(adC+4) = *(const int4*)(adjRow + pf + 4);

        u32 ev[8];
        *(uint4*)(ev)   = *(const uint4*)(&lds_e2[m0 + quad*8]);
        *(uint4*)(ev+4) = *(const uint4*)(&lds_e2[m0 + quad*8 + 4]);

        u32 pb[8];
        #pragma unroll
        for(int j=0;j<8;j++){
            float pp = e1pR * bflo(ev[j]);   // exp(f1)*exp(f2)     = exp(s)
            float pn = e1nR * bfhi(ev[j]);   // exp(.2f1)*exp(.2f2) = exp(.2s)
            float p  = (pp > 1.0f) ? pp : pn;          // lrelu: s>0 <=> exp(s)>1
            p = (adA[j] != 0) ? p : 0.0f;
            dsum += p;
            pb[j] = f2bf(p);
        }
        Frag af;
        af.u[0] = pb[0] | (pb[1]<<16);
        af.u[1] = pb[2] | (pb[3]<<16);
        af.u[2] = pb[4] | (pb[5]<<16);
        af.u[3] = pb[6] | (pb[7]<<16);

        const u16* bb = &xbuf[db][fh][lane*8];   // lane-linear: conflict-free ds_read_b128
        #pragma unroll
        for(int ct=0; ct<16; ct++){
            uint4 bw = *(const uint4*)(bb + ct*512);
            Frag bf_;
            bf_.u[0]=bw.x; bf_.u[1]=bw.y; bf_.u[2]=bw.z; bf_.u[3]=bw.w;
            acc[ct] = __builtin_amdgcn_mfma_f32_16x16x32_bf16(af.s, bf_.s, acc[ct], 0, 0, 0);
        }
        #pragma unroll
        for(int j=0;j<8;j++){ adA[j] = adB[j]; adB[j] = adC[j]; }
        db = (db==2) ? 0 : db+1;
    }

    // ---- softmax denominator: in-wave reduce over quads, broadcast to C-layout rows ----
    dsum += __shfl_xor(dsum, 16, 64);
    dsum += __shfl_xor(dsum, 32, 64);
    float invr[4];
    #pragma unroll
    for(int r=0;r<4;r++){
        float dr = __shfl(dsum, quad*4 + r, 64);
        invr[r] = 1.0f / fmaxf(dr, 1e-30f);
    }
    // ---- epilogue: scale, ELU, fp32 store ----
    #pragma unroll
    for(int ct=0; ct<16; ct++){
        #pragma unroll
        for(int r=0;r<4;r++){
            float v = acc[ct][r] * invr[r];
            v = (v > 0.f) ? v : (__expf(v) - 1.f);
            int n_out = n0 + nsub*16 + quad*4 + r;
            out[((size_t)(b*N_ + n_out))*F_ + fh*256 + ct*16 + r16] = v;
        }
    }
}

extern "C" void kernel_launch(void* const* d_in, const int* in_sizes, int n_in,
                              void* d_out, int out_size, void* d_ws, size_t ws_size,
                              hipStream_t stream) {
    const float* X  = (const float*)d_in[0];   // [16,1024,512] fp32
    const int* adj  = (const int*)d_in[1];     // [16,1024,1024] int32
    const float* W  = (const float*)d_in[2];   // [512,512] fp32
    const float* a1 = (const float*)d_in[3];   // [512]
    const float* a2 = (const float*)d_in[4];   // [512]
    float* out = (float*)d_out;                // [16,1024,512] fp32

    float* ws    = (float*)d_ws;
    float* d1acc = ws + 1024;                  // raw sums; exp'd inside k_main
    float* d2acc = ws + 1024 + 16384;
    u16*  XT     = (u16*)(ws + 50176);         // 16.78 MB bf16 [b][f][m]

    hipMemsetAsync(ws, 0, 33792*sizeof(float), stream);   // zero w1/w2 + d1acc + d2acc
    k_w12<<<64, 256, 0, stream>>>(W, a1, a2, ws);
    k_prep<<<dim3(16, 8, 16), 256, 0, stream>>>(X, ws, XT, d1acc, d2acc);
    k_main<<<dim3(16, 16), 512, 0, stream>>>(XT, adj, d1acc, d2acc, out);
}

// Round 4
// 193.455 us; speedup vs baseline: 1.1749x; 1.0195x over previous
//
#include <hip/hip_runtime.h>
#include <stdint.h>

typedef unsigned int u32;
typedef unsigned short u16;

#define N_  1024
#define F_  512
#define ALPHA 0.2f
#define TSTR 68   // k_prep LDS tile stride (u16): 136 B rows -> uint2-aligned reads, ~4-way write conflicts

typedef __attribute__((ext_vector_type(8))) short short8;
typedef __attribute__((ext_vector_type(4))) float float4v;

union Frag { short8 s; u32 u[4]; };

static __device__ __forceinline__ float bits2f(u32 b){ union{u32 u; float f;} c; c.u=b; return c.f; }
static __device__ __forceinline__ u32   f2bits(float f){ union{float f_; u32 u;} c; c.f_=f; return c.u; }
static __device__ __forceinline__ float bflo(u32 p){ return bits2f(p<<16); }
static __device__ __forceinline__ float bfhi(u32 p){ return bits2f(p & 0xffff0000u); }
static __device__ __forceinline__ u32   f2bf(float f){ u32 u=f2bits(f); return (u + 0x7fffu + ((u>>16)&1u))>>16; }
static __device__ __forceinline__ u32   cvt_pk_bf16(float lo, float hi){
    u32 r; asm("v_cvt_pk_bf16_f32 %0, %1, %2" : "=v"(r) : "v"(lo), "v"(hi)); return r;
}

// async global->LDS, 16 B per lane; LDS dest = wave-uniform base + lane*16
static __device__ __forceinline__ void gload_lds16(const void* g, void* l){
    __builtin_amdgcn_global_load_lds((const __attribute__((address_space(1))) u32*)g,
                                     (__attribute__((address_space(3))) u32*)l, 16, 0, 0);
}

// ---- kernel 1: w1 = W^T a1, w2 = W^T a2 (atomic partial sums into ws[0..1024)) ----
__global__ void k_w12(const float* __restrict__ W, const float* __restrict__ a1,
                      const float* __restrict__ a2, float* __restrict__ ws){
    int t = threadIdx.x;          // 256 threads: f = t and t+256
    int bo = blockIdx.x;          // 64 blocks: o-chunk of 8
    float s1a=0.f,s2a=0.f,s1b=0.f,s2b=0.f;
    #pragma unroll
    for(int i=0;i<8;i++){
        int o = bo*8+i;
        float av1 = a1[o], av2 = a2[o];
        float wa = W[o*F_ + t], wb = W[o*F_ + t + 256];
        s1a += wa*av1; s2a += wa*av2; s1b += wb*av1; s2b += wb*av2;
    }
    atomicAdd(&ws[t],       s1a); atomicAdd(&ws[512+t],     s2a);
    atomicAdd(&ws[t+256],   s1b); atomicAdd(&ws[512+t+256], s2b);
}

// ---- kernel 2: fused transpose + dot accumulation ----
// X fp32 [b][m][f] -> XT bf16 [b][f][m]; also d1acc[r] += X[r,:].w1, d2acc += X[r,:].w2 (fp32 atomics)
__global__ __launch_bounds__(256)
void k_prep(const float* __restrict__ X, const float* __restrict__ ws,
            u16* __restrict__ XT, float* __restrict__ d1acc, float* __restrict__ d2acc){
    __shared__ u16 tile[64*TSTR];
    const int t  = threadIdx.x;
    const int m0 = blockIdx.x*64, f0 = blockIdx.y*64, b = blockIdx.z;
    const int ml = t>>4, fl4 = (t&15)*4;
    float4 w1q = *(const float4*)(ws + f0 + fl4);
    float4 w2q = *(const float4*)(ws + 512 + f0 + fl4);
    float d1p[4], d2p[4];
    #pragma unroll
    for(int rr=0;rr<4;rr++){
        int m = ml + rr*16;
        float4 v = *(const float4*)(X + ((size_t)(b*N_ + m0 + m))*F_ + f0 + fl4);
        tile[(fl4+0)*TSTR + m] = (u16)f2bf(v.x);
        tile[(fl4+1)*TSTR + m] = (u16)f2bf(v.y);
        tile[(fl4+2)*TSTR + m] = (u16)f2bf(v.z);
        tile[(fl4+3)*TSTR + m] = (u16)f2bf(v.w);
        d1p[rr] = v.x*w1q.x + v.y*w1q.y + v.z*w1q.z + v.w*w1q.w;
        d2p[rr] = v.x*w2q.x + v.y*w2q.y + v.z*w2q.z + v.w*w2q.w;
    }
    #pragma unroll
    for(int s=1;s<16;s<<=1){
        #pragma unroll
        for(int rr=0;rr<4;rr++){ d1p[rr] += __shfl_xor(d1p[rr],s,64); d2p[rr] += __shfl_xor(d2p[rr],s,64); }
    }
    if((t&15)==0){
        #pragma unroll
        for(int rr=0;rr<4;rr++){
            atomicAdd(&d1acc[b*N_ + m0 + ml + rr*16], d1p[rr]);
            atomicAdd(&d2acc[b*N_ + m0 + ml + rr*16], d2p[rr]);
        }
    }
    __syncthreads();
    const int fl = t>>4, ml4 = (t&15)*4;
    #pragma unroll
    for(int rr=0;rr<4;rr++){
        int f = fl + rr*16;
        uint2 val = *(const uint2*)(&tile[f*TSTR + ml4]);
        *(uint2*)(XT + ((size_t)(b*F_ + f0 + f))*N_ + m0 + ml4) = val;
    }
}

// ---- kernel 3: fused scores+softmax+PV+ELU, producer/consumer P-sharing ----
// grid (16,16) = 256 blocks = 1 block/CU, 8 waves.
// PRODUCER role: wave w computes P (=exp-score) for rows [w*8, w*8+8) x 32 m ONCE,
//   packs bf16 A-fragments into pbuf (double-buffered, 4KB/buf). Halves score VALU +
//   adj loads vs the old per-fh duplication.
// CONSUMER role: wave (nsub=w&3, fh=w>>2) does 16 rows x 256 f: A-frag = 1 ds_read_b128
//   from pbuf, B from xbuf, 16 MFMA.
// Memory: triple-buffered xbuf staging (distance 2), uniform 5 VMEM/body (1 adj + 4
//   gload_lds) -> counted "s_waitcnt vmcnt(4) lgkmcnt(0); s_barrier" at loop top is the
//   ONLY barrier per iter (covers staging drain + P-write visibility).
// XCD affinity: all 16 n-blocks of batch b on one XCD -> XT L2-resident.
__global__ __launch_bounds__(512, 2)
void k_main(const u16* __restrict__ XT, const int* __restrict__ adj,
            const float* __restrict__ d1acc, const float* __restrict__ d2acc,
            float* __restrict__ out){
    __shared__ u16 xbuf[3][2][8192];   // 96 KB triple-buffered X tiles
    __shared__ u32 lds_e2[N_];         // 4 KB exp(f2)/exp(.2 f2) bf16-pair table
    __shared__ u16 pbuf[2][4][512];    // 8 KB P A-fragments [buf][nsub][lane*8]
    __shared__ float dsums[64];        // row softmax denominators

    const int t    = threadIdx.x;
    const int lane = t & 63;
    const int wv   = t >> 6;           // 0..7
    const int nsub = wv & 3;           // consumer: row-group of 16
    const int fh   = wv >> 2;          // consumer: f-half of 256
    const int id   = blockIdx.x + (blockIdx.y << 4);
    const int xcd  = id & 7, slot = id >> 3;
    const int b    = (xcd << 1) | (slot >> 4);
    const int n0   = (slot & 15) << 6;
    const int r16  = lane & 15;
    const int quad = lane >> 4;
    // producer lane mapping: row octet rowL = lane>>3 (0..7), m-quad qL = lane&7
    const int rowL = lane >> 3;
    const int qL   = lane & 7;

    // build exp(f2)/exp(.2*f2) bf16-pair table in LDS; 2 entries/thread
    {
        float2 dv = *(const float2*)(d2acc + (size_t)b*N_ + t*2);
        lds_e2[t*2]   = f2bf(__expf(dv.x)) | (f2bf(__expf(ALPHA*dv.x))<<16);
        lds_e2[t*2+1] = f2bf(__expf(dv.y)) | (f2bf(__expf(ALPHA*dv.y))<<16);
    }
    // producer per-lane constants: its row's exp(f1) pair, adj base
    const float d1v  = d1acc[b*N_ + n0 + wv*8 + rowL];
    const float e1pL = __expf(d1v);
    const float e1nL = __expf(ALPHA*d1v);
    const int* adjLane = adj + ((size_t)(b*N_ + n0 + wv*8 + rowL))*N_ + qL*4;
    const u16* XTb = XT + (size_t)b*F_*N_;

    float dsum = 0.f;
    const int ltP = (wv&1)*8 + rowL + (qL>>1)*16;   // P-frag target lane index

    // producer: P for chunk c (cols c*32..+31) -> pbuf[pb]; 4 values/lane
    auto produce = [&](int c, int pb, int4 ad){
        uint4 ev = *(const uint4*)(&lds_e2[c*32 + qL*4]);
        float p0 = fmaxf(e1pL*bflo(ev.x), e1nL*bfhi(ev.x)); p0 = ad.x ? p0 : 0.f;
        float p1 = fmaxf(e1pL*bflo(ev.y), e1nL*bfhi(ev.y)); p1 = ad.y ? p1 : 0.f;
        float p2 = fmaxf(e1pL*bflo(ev.z), e1nL*bfhi(ev.z)); p2 = ad.z ? p2 : 0.f;
        float p3 = fmaxf(e1pL*bflo(ev.w), e1nL*bfhi(ev.w)); p3 = ad.w ? p3 : 0.f;
        dsum += (p0+p1) + (p2+p3);
        uint2 w; w.x = cvt_pk_bf16(p0,p1); w.y = cvt_pk_bf16(p2,p3);
        *(uint2*)(&pbuf[pb][wv>>1][ltP*8 + (qL&1)*4]) = w;
    };
    // stage X chunk (32 m) into a buffer: 4 gload_lds per wave (32 total over 8 waves)
    auto stage = [&](int mcol, u16 (*buf)[8192]){
        #pragma unroll
        for(int k=0;k<4;k++){
            int idx = wv*4 + k, fhh = idx>>4, c = idx&15;
            const u16* g = XTb + (size_t)(fhh*256 + c*16 + r16)*N_ + mcol + quad*8;
            gload_lds16(g, &buf[fhh][c*512]);
        }
    };

    __syncthreads();                       // lds_e2 ready
    {   // prologue: P[0] (direct adj load), then stage chunks 0,1 + prefetch adj[1]
        int4 ad0 = *(const int4*)(adjLane);
        produce(0, 0, ad0);
    }
    stage(0,  xbuf[0]);
    int4 adU = *(const int4*)(adjLane + 32);   // adj chunk 1, used in body 0
    stage(32, xbuf[1]);
    asm volatile("s_waitcnt lgkmcnt(0)" ::: "memory");   // P[0] writes committed
    __syncthreads();                       // P[0] visible; staging counted from here

    float4v acc[16];
    #pragma unroll
    for(int i=0;i<16;i++) acc[i] = (float4v){0.f,0.f,0.f,0.f};

    int db = 0;
    for(int i=0;i<32;i++){
        const int m0 = i*32;
        // xbuf[db] staged 2 bodies ago (drained: depth>=5), own P-writes flushed, barrier
        asm volatile("s_waitcnt vmcnt(4) lgkmcnt(0)\n\ts_barrier" ::: "memory");

        // body VMEM: 1 adj (chunk i+2) + 4 gload_lds (chunk i+2); wrapped dummies at tail
        const int ms = (m0 + 64) & (N_-1);
        int4 adV = *(const int4*)(adjLane + ms);
        int dbw = db + 2; if(dbw >= 3) dbw -= 3;
        stage(ms, xbuf[dbw]);

        // produce P[i+1] -> pbuf[(i+1)&1] (uses adU = adj[i+1], loaded last body)
        if(i < 31) produce(i+1, (i+1)&1, adU);

        // consume: A-frag from pbuf[i&1], B from xbuf[db], 16 MFMA
        Frag af;
        {
            uint4 aw = *(const uint4*)(&pbuf[i&1][nsub][lane*8]);
            af.u[0]=aw.x; af.u[1]=aw.y; af.u[2]=aw.z; af.u[3]=aw.w;
        }
        const u16* bb = &xbuf[db][fh][lane*8];   // lane-linear: conflict-free ds_read_b128
        #pragma unroll
        for(int ct=0; ct<16; ct++){
            uint4 bw = *(const uint4*)(bb + ct*512);
            Frag bf_;
            bf_.u[0]=bw.x; bf_.u[1]=bw.y; bf_.u[2]=bw.z; bf_.u[3]=bw.w;
            acc[ct] = __builtin_amdgcn_mfma_f32_16x16x32_bf16(af.s, bf_.s, acc[ct], 0, 0, 0);
        }
        adU = adV;
        db = (db==2) ? 0 : db+1;
    }

    // ---- softmax denominators: reduce producer partials over m-quads (lane bits 0..2) ----
    asm volatile("s_waitcnt vmcnt(0) lgkmcnt(0)" ::: "memory");   // drain tail dummy DMAs
    dsum += __shfl_xor(dsum, 1, 64);
    dsum += __shfl_xor(dsum, 2, 64);
    dsum += __shfl_xor(dsum, 4, 64);
    if(qL == 0) dsums[wv*8 + rowL] = dsum;
    __syncthreads();
    float invr[4];
    #pragma unroll
    for(int r=0;r<4;r++) invr[r] = 1.0f / fmaxf(dsums[nsub*16 + quad*4 + r], 1e-30f);

    // ---- epilogue: scale, ELU, fp32 store ----
    #pragma unroll
    for(int ct=0; ct<16; ct++){
        #pragma unroll
        for(int r=0;r<4;r++){
            float v = acc[ct][r] * invr[r];
            v = (v > 0.f) ? v : (__expf(v) - 1.f);
            int n_out = n0 + nsub*16 + quad*4 + r;
            out[((size_t)(b*N_ + n_out))*F_ + fh*256 + ct*16 + r16] = v;
        }
    }
}

extern "C" void kernel_launch(void* const* d_in, const int* in_sizes, int n_in,
                              void* d_out, int out_size, void* d_ws, size_t ws_size,
                              hipStream_t stream) {
    const float* X  = (const float*)d_in[0];   // [16,1024,512] fp32
    const int* adj  = (const int*)d_in[1];     // [16,1024,1024] int32
    const float* W  = (const float*)d_in[2];   // [512,512] fp32
    const float* a1 = (const float*)d_in[3];   // [512]
    const float* a2 = (const float*)d_in[4];   // [512]
    float* out = (float*)d_out;                // [16,1024,512] fp32

    float* ws    = (float*)d_ws;
    float* d1acc = ws + 1024;                  // raw sums; exp'd inside k_main
    float* d2acc = ws + 1024 + 16384;
    u16*  XT     = (u16*)(ws + 50176);         // 16.78 MB bf16 [b][f][m]

    hipMemsetAsync(ws, 0, 33792*sizeof(float), stream);   // zero w1/w2 + d1acc + d2acc
    k_w12<<<64, 256, 0, stream>>>(W, a1, a2, ws);
    k_prep<<<dim3(16, 8, 16), 256, 0, stream>>>(X, ws, XT, d1acc, d2acc);
    k_main<<<dim3(16, 16), 512, 0, stream>>>(XT, adj, d1acc, d2acc, out);
}

// Round 5
// 181.518 us; speedup vs baseline: 1.2522x; 1.0658x over previous
//
#include <hip/hip_runtime.h>
#include <stdint.h>

typedef unsigned int u32;
typedef unsigned short u16;

#define N_  1024
#define F_  512
#define ALPHA 0.2f
#define TSTR 68   // k_prep LDS tile stride (u16): 136 B rows -> uint2-aligned reads, ~4-way write conflicts

typedef __attribute__((ext_vector_type(8))) short short8;
typedef __attribute__((ext_vector_type(4))) float float4v;

union Frag { short8 s; u32 u[4]; };

static __device__ __forceinline__ float bits2f(u32 b){ union{u32 u; float f;} c; c.u=b; return c.f; }
static __device__ __forceinline__ u32   f2bits(float f){ union{float f_; u32 u;} c; c.f_=f; return c.u; }
static __device__ __forceinline__ float bflo(u32 p){ return bits2f(p<<16); }
static __device__ __forceinline__ float bfhi(u32 p){ return bits2f(p & 0xffff0000u); }
static __device__ __forceinline__ u32   f2bf(float f){ u32 u=f2bits(f); return (u + 0x7fffu + ((u>>16)&1u))>>16; }
static __device__ __forceinline__ u32   cvt_pk_bf16(float lo, float hi){
    u32 r; asm("v_cvt_pk_bf16_f32 %0, %1, %2" : "=v"(r) : "v"(lo), "v"(hi)); return r;
}

// async global->LDS, 16 B per lane; LDS dest = wave-uniform base + lane*16
static __device__ __forceinline__ void gload_lds16(const void* g, void* l){
    __builtin_amdgcn_global_load_lds((const __attribute__((address_space(1))) u32*)g,
                                     (__attribute__((address_space(3))) u32*)l, 16, 0, 0);
}

// ---- kernel 1: w1 = W^T a1, w2 = W^T a2 (atomic partial sums into ws[0..1024)) ----
__global__ void k_w12(const float* __restrict__ W, const float* __restrict__ a1,
                      const float* __restrict__ a2, float* __restrict__ ws){
    int t = threadIdx.x;          // 256 threads: f = t and t+256
    int bo = blockIdx.x;          // 64 blocks: o-chunk of 8
    float s1a=0.f,s2a=0.f,s1b=0.f,s2b=0.f;
    #pragma unroll
    for(int i=0;i<8;i++){
        int o = bo*8+i;
        float av1 = a1[o], av2 = a2[o];
        float wa = W[o*F_ + t], wb = W[o*F_ + t + 256];
        s1a += wa*av1; s2a += wa*av2; s1b += wb*av1; s2b += wb*av2;
    }
    atomicAdd(&ws[t],       s1a); atomicAdd(&ws[512+t],     s2a);
    atomicAdd(&ws[t+256],   s1b); atomicAdd(&ws[512+t+256], s2b);
}

// ---- kernel 2: fused transpose + dot accumulation ----
// X fp32 [b][m][f] -> XT bf16 [b][f][m]; also d1acc[r] += X[r,:].w1, d2acc += X[r,:].w2 (fp32 atomics)
__global__ __launch_bounds__(256)
void k_prep(const float* __restrict__ X, const float* __restrict__ ws,
            u16* __restrict__ XT, float* __restrict__ d1acc, float* __restrict__ d2acc){
    __shared__ u16 tile[64*TSTR];
    const int t  = threadIdx.x;
    const int m0 = blockIdx.x*64, f0 = blockIdx.y*64, b = blockIdx.z;
    const int ml = t>>4, fl4 = (t&15)*4;
    float4 w1q = *(const float4*)(ws + f0 + fl4);
    float4 w2q = *(const float4*)(ws + 512 + f0 + fl4);
    float d1p[4], d2p[4];
    #pragma unroll
    for(int rr=0;rr<4;rr++){
        int m = ml + rr*16;
        float4 v = *(const float4*)(X + ((size_t)(b*N_ + m0 + m))*F_ + f0 + fl4);
        tile[(fl4+0)*TSTR + m] = (u16)f2bf(v.x);
        tile[(fl4+1)*TSTR + m] = (u16)f2bf(v.y);
        tile[(fl4+2)*TSTR + m] = (u16)f2bf(v.z);
        tile[(fl4+3)*TSTR + m] = (u16)f2bf(v.w);
        d1p[rr] = v.x*w1q.x + v.y*w1q.y + v.z*w1q.z + v.w*w1q.w;
        d2p[rr] = v.x*w2q.x + v.y*w2q.y + v.z*w2q.z + v.w*w2q.w;
    }
    #pragma unroll
    for(int s=1;s<16;s<<=1){
        #pragma unroll
        for(int rr=0;rr<4;rr++){ d1p[rr] += __shfl_xor(d1p[rr],s,64); d2p[rr] += __shfl_xor(d2p[rr],s,64); }
    }
    if((t&15)==0){
        #pragma unroll
        for(int rr=0;rr<4;rr++){
            atomicAdd(&d1acc[b*N_ + m0 + ml + rr*16], d1p[rr]);
            atomicAdd(&d2acc[b*N_ + m0 + ml + rr*16], d2p[rr]);
        }
    }
    __syncthreads();
    const int fl = t>>4, ml4 = (t&15)*4;
    #pragma unroll
    for(int rr=0;rr<4;rr++){
        int f = fl + rr*16;
        uint2 val = *(const uint2*)(&tile[f*TSTR + ml4]);
        *(uint2*)(XT + ((size_t)(b*F_ + f0 + f))*N_ + m0 + ml4) = val;
    }
}

// ---- kernel 3: fused scores+softmax+PV+ELU, producer/consumer, 16 waves ----
// grid (16,16) = 256 blocks = 1 block/CU, 1024 threads = 16 waves = 4 waves/SIMD.
// Same total work as the 8-wave version, re-partitioned for 2x TLP (latency-bound fix):
//   PRODUCER: wave w -> rows [w*4, w*4+4) x 32 m, 2 P-values/lane (1 adj int2/lane).
//   CONSUMER: wave (nsub=w&3, fq=w>>2) -> 16 rows x 128 f: acc[8], 8 MFMA/iter.
// Per-body VMEM/wave = 3 (1 adj + 2 gload_lds); triple-buffered staging distance 2;
// counted "s_waitcnt vmcnt(2) lgkmcnt(0); s_barrier" at loop top is the only barrier:
//   after vmcnt(2) the 2 newest ops (prev body's stages, chunk i+1) stay in flight;
//   chunk i (staged 2 bodies ago) and prev body's adj are drained. lgkmcnt(0)+barrier
//   publishes pbuf[i&1] written last body.
// XCD affinity: all 16 n-blocks of batch b on one XCD -> XT L2-resident.
__global__ __launch_bounds__(1024, 4)
void k_main(const u16* __restrict__ XT, const int* __restrict__ adj,
            const float* __restrict__ d1acc, const float* __restrict__ d2acc,
            float* __restrict__ out){
    __shared__ u16 xbuf[3][2][8192];   // 96 KB triple-buffered X tiles
    __shared__ u32 lds_e2[N_];         // 4 KB exp(f2)/exp(.2 f2) bf16-pair table
    __shared__ u16 pbuf[2][4][512];    // 8 KB P A-fragments [buf][nsub][lane*8]
    __shared__ float dsums[64];        // row softmax denominators

    const int t    = threadIdx.x;
    const int lane = t & 63;
    const int wv   = t >> 6;           // 0..15
    const int nsub = wv & 3;           // consumer: row-group of 16
    const int fq   = wv >> 2;          // consumer: f-quarter of 128
    const int id   = blockIdx.x + (blockIdx.y << 4);
    const int xcd  = id & 7, slot = id >> 3;
    const int b    = (xcd << 1) | (slot >> 4);
    const int n0   = (slot & 15) << 6;
    const int r16  = lane & 15;
    const int quad = lane >> 4;
    const int rowL = lane >> 4;        // producer: row 0..3 within wave's quartet
    const int qL   = lane & 15;        // producer: col-pair index (cols qL*2, qL*2+1)

    // exp(f2)/exp(.2*f2) bf16-pair table: 1 entry/thread
    {
        float dv = d2acc[(size_t)b*N_ + t];
        lds_e2[t] = f2bf(__expf(dv)) | (f2bf(__expf(ALPHA*dv))<<16);
    }
    const float d1v  = d1acc[b*N_ + n0 + wv*4 + rowL];
    const float e1pL = __expf(d1v);
    const float e1nL = __expf(ALPHA*d1v);
    const int* adjLane = adj + ((size_t)(b*N_ + n0 + wv*4 + rowL))*N_ + qL*2;
    const u16* XTb = XT + (size_t)b*F_*N_;

    float dsum = 0.f;
    // P store: row16 = (wv&3)*4+rowL; k = qL*2+{0,1}; lane = row16+(k>>3)*16; u16 off = lane*8 + k%8
    const int pOff = ((wv&3)*4 + rowL + (qL>>2)*16)*8 + (qL&3)*2;

    auto produce = [&](int c, int pb, int2 ad){
        uint2 ev = *(const uint2*)(&lds_e2[c*32 + qL*2]);
        float p0 = fmaxf(e1pL*bflo(ev.x), e1nL*bfhi(ev.x)); p0 = ad.x ? p0 : 0.f;
        float p1 = fmaxf(e1pL*bflo(ev.y), e1nL*bfhi(ev.y)); p1 = ad.y ? p1 : 0.f;
        dsum += p0 + p1;
        *(u32*)(&pbuf[pb][wv>>2][pOff]) = cvt_pk_bf16(p0, p1);
    };
    auto stage = [&](int mcol, u16 (*buf)[8192]){
        #pragma unroll
        for(int k=0;k<2;k++){
            int idx = wv*2 + k, fhh = idx>>4, c = idx&15;
            const u16* g = XTb + (size_t)(fhh*256 + c*16 + r16)*N_ + mcol + quad*8;
            gload_lds16(g, &buf[fhh][c*512]);
        }
    };

    __syncthreads();                       // lds_e2 ready
    { int2 ad0 = *(const int2*)(adjLane); produce(0, 0, ad0); }
    stage(0,  xbuf[0]);
    int2 adU = *(const int2*)(adjLane + 32);   // adj chunk 1
    stage(32, xbuf[1]);
    asm volatile("s_waitcnt lgkmcnt(0)" ::: "memory");
    __syncthreads();                       // P[0] + chunks 0,1 resident (full drain, one-time)

    float4v acc[8];
    #pragma unroll
    for(int i=0;i<8;i++) acc[i] = (float4v){0.f,0.f,0.f,0.f};

    int db = 0;
    for(int i=0;i<32;i++){
        asm volatile("s_waitcnt vmcnt(2) lgkmcnt(0)\n\ts_barrier" ::: "memory");

        // body VMEM (uniform 3/wave): adj chunk i+2, stage chunk i+2 (dummies wrap at tail)
        const int ms = (i*32 + 64) & (N_-1);
        int2 adV = *(const int2*)(adjLane + ms);
        int dbw = db + 2; if(dbw >= 3) dbw -= 3;
        stage(ms, xbuf[dbw]);

        if(i < 31) produce(i+1, (i+1)&1, adU);   // P[i+1] from adj[i+1] (loaded last body)

        Frag af;
        { uint4 aw = *(const uint4*)(&pbuf[i&1][nsub][lane*8]);
          af.u[0]=aw.x; af.u[1]=aw.y; af.u[2]=aw.z; af.u[3]=aw.w; }
        const u16* bb = &xbuf[db][fq>>1][(fq&1)*8*512 + lane*8];   // lane-linear ds_read_b128
        #pragma unroll
        for(int ct=0; ct<8; ct++){
            uint4 bw = *(const uint4*)(bb + ct*512);
            Frag bf_; bf_.u[0]=bw.x; bf_.u[1]=bw.y; bf_.u[2]=bw.z; bf_.u[3]=bw.w;
            acc[ct] = __builtin_amdgcn_mfma_f32_16x16x32_bf16(af.s, bf_.s, acc[ct], 0, 0, 0);
        }
        adU = adV;
        db = (db==2) ? 0 : db+1;
    }

    // ---- softmax denominators: reduce over qL (lane bits 0..3), one value per row ----
    asm volatile("s_waitcnt vmcnt(0) lgkmcnt(0)" ::: "memory");   // drain tail dummy DMAs
    dsum += __shfl_xor(dsum, 1, 64);
    dsum += __shfl_xor(dsum, 2, 64);
    dsum += __shfl_xor(dsum, 4, 64);
    dsum += __shfl_xor(dsum, 8, 64);
    if(qL == 0) dsums[wv*4 + rowL] = dsum;
    __syncthreads();
    float invr[4];
    #pragma unroll
    for(int r=0;r<4;r++) invr[r] = 1.0f / fmaxf(dsums[nsub*16 + quad*4 + r], 1e-30f);

    // ---- epilogue: scale, ELU, fp32 store ----
    #pragma unroll
    for(int ct=0; ct<8; ct++){
        #pragma unroll
        for(int r=0;r<4;r++){
            float v = acc[ct][r] * invr[r];
            v = (v > 0.f) ? v : (__expf(v) - 1.f);
            int n_out = n0 + nsub*16 + quad*4 + r;
            out[((size_t)(b*N_ + n_out))*F_ + fq*128 + ct*16 + r16] = v;
        }
    }
}

extern "C" void kernel_launch(void* const* d_in, const int* in_sizes, int n_in,
                              void* d_out, int out_size, void* d_ws, size_t ws_size,
                              hipStream_t stream) {
    const float* X  = (const float*)d_in[0];   // [16,1024,512] fp32
    const int* adj  = (const int*)d_in[1];     // [16,1024,1024] int32
    const float* W  = (const float*)d_in[2];   // [512,512] fp32
    const float* a1 = (const float*)d_in[3];   // [512]
    const float* a2 = (const float*)d_in[4];   // [512]
    float* out = (float*)d_out;                // [16,1024,512] fp32

    float* ws    = (float*)d_ws;
    float* d1acc = ws + 1024;                  // raw sums; exp'd inside k_main
    float* d2acc = ws + 1024 + 16384;
    u16*  XT     = (u16*)(ws + 50176);         // 16.78 MB bf16 [b][f][m]

    hipMemsetAsync(ws, 0, 33792*sizeof(float), stream);   // zero w1/w2 + d1acc + d2acc
    k_w12<<<64, 256, 0, stream>>>(W, a1, a2, ws);
    k_prep<<<dim3(16, 8, 16), 256, 0, stream>>>(X, ws, XT, d1acc, d2acc);
    k_main<<<dim3(16, 16), 1024, 0, stream>>>(XT, adj, d1acc, d2acc, out);
}